// Round 1
// baseline (28122.186 us; speedup 1.0000x reference)
//
#include <hip/hip_runtime.h>
#include <stdint.h>

// Problem dims
#define BB 32
#define SS 2048
#define II 128
#define HH 512
#define OO 128

// Block roles
#define NA 32
#define NB 32
#define NY 4
#define NBLK (NA + NB + NY)
#define PHASES (SS + 2)   // p = 0 .. S+1
#define THREADS 256

// Workspace layout (bytes)
#define CNT_OFF 0
#define H0_OFF  16384
#define H1_OFF  (16384 + 65536)
#define WS_BYTES (16384 + 2 * 65536)

// LDS: 96KB weight frags + 6KB cross-wave reduce
#define REDOFF 98304
#define LDS_BYTES (98304 + 6144)

typedef __attribute__((ext_vector_type(8))) short short8;   // 8 x bf16
typedef __attribute__((ext_vector_type(4))) float f32x4;

__device__ __forceinline__ short f2bf(float f) {
  unsigned int u = __float_as_uint(f);
  u += 0x7fffu + ((u >> 16) & 1u);        // RNE
  return (short)(u >> 16);
}
__device__ __forceinline__ float sigm(float v) { return 1.0f / (1.0f + __expf(-v)); }
__device__ __forceinline__ float tanhc(float v) {
  v = fminf(fmaxf(v, -15.0f), 15.0f);
  float e = __expf(2.0f * v);
  return (e - 1.0f) / (e + 1.0f);
}

__global__ __launch_bounds__(THREADS, 1)
void gru_persist(const float* __restrict__ x,
                 const float* __restrict__ wx0, const float* __restrict__ bx0,
                 const float* __restrict__ wh0,
                 const float* __restrict__ wx1, const float* __restrict__ bx1,
                 const float* __restrict__ wh1,
                 const float* __restrict__ wy,  const float* __restrict__ by,
                 float* __restrict__ out, unsigned char* __restrict__ ws)
{
  extern __shared__ char smem[];
  short8* ldsw = (short8*)smem;                 // weight frags: frag f at byte f*1024 + lane*16
  float*  red  = (float*)(smem + REDOFF);       // cross-wave partial-acc reduce

  unsigned int*   cnt    = (unsigned int*)(ws + CNT_OFF);     // per-phase arrival counters
  unsigned short* pubH0  = (unsigned short*)(ws + H0_OFF);    // [2][B][H] bf16
  unsigned short* pubH1  = (unsigned short*)(ws + H1_OFF);    // [2][B][H] bf16

  const int tid = threadIdx.x;
  const int l   = tid & 63;
  const int wv  = tid >> 6;
  const int lr  = l & 15;      // lane row/col within 16-tile
  const int lg  = l >> 4;      // lane k-group
  const int bid = blockIdx.x;
  const int role = (bid < NA) ? 0 : (bid < NA + NB) ? 1 : 2;

  // ---------- one-time weight preload into LDS, MFMA B-fragment order ----------
  if (role == 0) {
    const int ua = bid * 16;
    for (int f = wv; f < 60; f += 4) {          // 3 gate-tiles x 20 k-tiles (K=128 x + 512 h)
      const int nt = f / 20, kt = f % 20;
      const int row = nt * 512 + ua + lr;
      const float* src = (kt < 4) ? (wx0 + (size_t)row * II + kt * 32 + lg * 8)
                                  : (wh0 + (size_t)row * HH + (kt - 4) * 32 + lg * 8);
      short8 v;
#pragma unroll
      for (int j = 0; j < 8; ++j) v[j] = f2bf(src[j]);
      ldsw[(f << 6) + l] = v;
    }
  } else if (role == 1) {
    const int ub = (bid - NA) * 16;
    for (int f = wv; f < 96; f += 4) {          // 3 gate-tiles x 32 k-tiles (K=512 x + 512 h)
      const int nt = f >> 5, kt = f & 31;
      const int row = nt * 512 + ub + lr;
      const float* src = (kt < 16) ? (wx1 + (size_t)row * HH + kt * 32 + lg * 8)
                                   : (wh1 + (size_t)row * HH + (kt - 16) * 32 + lg * 8);
      short8 v;
#pragma unroll
      for (int j = 0; j < 8; ++j) v[j] = f2bf(src[j]);
      ldsw[(f << 6) + l] = v;
    }
  } else {
    const int oy = (bid - NA - NB) * 32;
    for (int f = wv; f < 32; f += 4) {          // 2 out-tiles x 16 k-tiles
      const int nt = f >> 4, kt = f & 15;
      const int row = oy + nt * 16 + lr;
      const float* src = wy + (size_t)row * HH + kt * 32 + lg * 8;
      short8 v;
#pragma unroll
      for (int j = 0; j < 8; ++j) v[j] = f2bf(src[j]);
      ldsw[(f << 6) + l] = v;
    }
  }
  __syncthreads();

  // wave roles: mh = batch half (0:b0-15, 1:b16-31), kh = K half (split-K)
  const int mh = wv & 1;
  const int kh = wv >> 1;
  const int bA = mh * 16 + lr;         // batch index for A-fragment loads
  const int bC = mh * 16 + lg * 4;     // batch base for C-fragment rows

  int u0 = 0, KT = 20, KXT = 4, ktlo = 0, kthi = 0;
  float bz = 0.f, brr = 0.f, bg = 0.f;
  if (role == 0) { u0 = bid * 16;        KT = 20; KXT = 4;  ktlo = kh ? 10 : 0; kthi = kh ? 20 : 10; }
  else if (role == 1) { u0 = (bid - NA) * 16; KT = 32; KXT = 16; ktlo = kh ? 16 : 0; kthi = kh ? 32 : 16; }
  if (role <= 1 && kh == 0) {
    const float* bx = role ? bx1 : bx0;
    bz  = bx[u0 + lr];
    brr = bx[512 + u0 + lr];
    bg  = bx[1024 + u0 + lr];
  }
  int oy = 0;
  const int ynt = wv >> 1;
  float byv = 0.f;
  if (role == 2) { oy = (bid - NA - NB) * 32; byv = by[oy + ynt * 16 + lr]; }

  f32x4 hm = {0.f, 0.f, 0.f, 0.f};    // fp32 master h slice (kh0 waves of roles 0/1)

  for (int p = 0; p < PHASES; ++p) {
    // ---- wait for all blocks to finish phase p-1 ----
    if (p > 0) {
      if (tid == 0) {
        while (__hip_atomic_load(&cnt[p - 1], __ATOMIC_RELAXED, __HIP_MEMORY_SCOPE_AGENT) < NBLK)
          __builtin_amdgcn_s_sleep(1);
      }
      __syncthreads();
      __threadfence();   // acquire: invalidate L1/L2 so cross-XCD publishes are visible
    }

    const bool act01 = (role == 0) ? (p < SS) : (p >= 1 && p <= SS);
    if (role <= 1 && act01) {
      // layer0 @ phase p computes h0(p): x-input x_p, h-input h0(p-1)
      // layer1 @ phase p computes h1(p-1): x-input h0(p-1), h-input h1(p-2)
      const unsigned short* pubA  = pubH0 + ((size_t)((p - 1) & 1)) * (BB * HH);
      const unsigned short* pubB2 = pubH1 + ((size_t)(p & 1)) * (BB * HH);

      f32x4 aZ = {0,0,0,0}, aR = {0,0,0,0}, aG1 = {0,0,0,0}, aG2 = {0,0,0,0};
      for (int kt = ktlo; kt < kthi; ++kt) {
        short8 af;
        if (role == 0) {
          if (kt < 4) {
            const float* xp = x + (size_t)bA * (SS * II) + (size_t)p * II + kt * 32 + lg * 8;
#pragma unroll
            for (int j = 0; j < 8; ++j) af[j] = f2bf(xp[j]);
          } else {
            af = *(const short8*)(pubA + (size_t)bA * HH + (kt - 4) * 32 + lg * 8);
          }
        } else {
          if (kt < 16) af = *(const short8*)(pubA  + (size_t)bA * HH + kt * 32 + lg * 8);
          else         af = *(const short8*)(pubB2 + (size_t)bA * HH + (kt - 16) * 32 + lg * 8);
        }
        short8 wz = ldsw[((0 * KT + kt) << 6) + l];
        short8 wr = ldsw[((1 * KT + kt) << 6) + l];
        short8 wg = ldsw[((2 * KT + kt) << 6) + l];
        aZ = __builtin_amdgcn_mfma_f32_16x16x32_bf16(af, wz, aZ, 0, 0, 0);
        aR = __builtin_amdgcn_mfma_f32_16x16x32_bf16(af, wr, aR, 0, 0, 0);
        if (kt < KXT) aG1 = __builtin_amdgcn_mfma_f32_16x16x32_bf16(af, wg, aG1, 0, 0, 0);
        else          aG2 = __builtin_amdgcn_mfma_f32_16x16x32_bf16(af, wg, aG2, 0, 0, 0);
      }
      if (kh == 1) {   // publish split-K partials to LDS
#pragma unroll
        for (int r = 0; r < 4; ++r) {
          red[((mh * 3 + 0) * 4 + r) * 64 + l] = aZ[r];
          red[((mh * 3 + 1) * 4 + r) * 64 + l] = aR[r];
          red[((mh * 3 + 2) * 4 + r) * 64 + l] = aG2[r];
        }
      }
      __syncthreads();
      if (kh == 0) {   // combine + gates + publish
        unsigned short* pubO = role ? (pubH1 + ((size_t)((p - 1) & 1)) * (BB * HH))
                                    : (pubH0 + ((size_t)(p & 1)) * (BB * HH));
        const bool fin = role ? (p == SS) : (p == SS - 1);
#pragma unroll
        for (int r = 0; r < 4; ++r) {
          const float z2 = red[((mh * 3 + 0) * 4 + r) * 64 + l];
          const float r2 = red[((mh * 3 + 1) * 4 + r) * 64 + l];
          const float g2 = red[((mh * 3 + 2) * 4 + r) * 64 + l];
          const float zz = sigm(aZ[r] + z2 + bz);
          const float rr = sigm(aR[r] + r2 + brr);
          const float gg = tanhc(aG1[r] + bg + rr * (aG2[r] + g2));  // g = tanh(xg + bg + r*hg)
          const float hn = gg + zz * (hm[r] - gg);
          hm[r] = hn;
          pubO[(size_t)(bC + r) * HH + u0 + lr] = (unsigned short)f2bf(hn);
          if (fin)
            out[(size_t)(BB * SS * OO) + (size_t)(bC + r) * (2 * HH) + (role ? HH : 0) + u0 + lr] = hn;
        }
      }
    } else if (role == 2 && p >= 2) {
      // y(p-2) = h1(p-2) @ wy^T + by
      const unsigned short* pubV = pubH1 + ((size_t)(p & 1)) * (BB * HH);
      f32x4 acc = {0,0,0,0};
      for (int kt = 0; kt < 16; ++kt) {
        short8 af = *(const short8*)(pubV + (size_t)bA * HH + kt * 32 + lg * 8);
        short8 bw = ldsw[((ynt * 16 + kt) << 6) + l];
        acc = __builtin_amdgcn_mfma_f32_16x16x32_bf16(af, bw, acc, 0, 0, 0);
      }
#pragma unroll
      for (int r = 0; r < 4; ++r) {
        out[(size_t)(bC + r) * (SS * OO) + (size_t)(p - 2) * OO + oy + ynt * 16 + lr] = acc[r] + byv;
      }
    }

    // ---- arrive at phase p ----
    __syncthreads();   // drains all waves' vmem stores before the fence
    if (tid == 0) {
      __threadfence(); // release: write back L2 so other XCDs can see our publishes
      __hip_atomic_fetch_add(&cnt[p], 1u, __ATOMIC_RELEASE, __HIP_MEMORY_SCOPE_AGENT);
    }
  }
}

extern "C" void kernel_launch(void* const* d_in, const int* in_sizes, int n_in,
                              void* d_out, int out_size, void* d_ws, size_t ws_size,
                              hipStream_t stream) {
  (void)in_sizes; (void)n_in; (void)out_size;
  const float* x   = (const float*)d_in[0];
  const float* wx0 = (const float*)d_in[1];
  const float* bx0 = (const float*)d_in[2];
  const float* wh0 = (const float*)d_in[3];
  const float* wx1 = (const float*)d_in[4];
  const float* bx1 = (const float*)d_in[5];
  const float* wh1 = (const float*)d_in[6];
  const float* wy  = (const float*)d_in[7];
  const float* by  = (const float*)d_in[8];
  float* out = (float*)d_out;

  // zero phase counters + h publish buffers (makes every launch/replay identical)
  hipMemsetAsync(d_ws, 0, WS_BYTES, stream);
  gru_persist<<<dim3(NBLK), dim3(THREADS), LDS_BYTES, stream>>>(
      x, wx0, bx0, wh0, wx1, bx1, wh1, wy, by, out, (unsigned char*)d_ws);
  (void)ws_size;
}

// Round 2
// 13842.535 us; speedup vs baseline: 2.0316x; 2.0316x over previous
//
#include <hip/hip_runtime.h>
#include <stdint.h>

// Problem dims
#define BB 32
#define SS 2048
#define II 128
#define HH 512
#define OO 128

// Block roles
#define NA 32
#define NB 32
#define NY 4
#define NBLK (NA + NB + NY)
#define PHASES (SS + 2)   // p = 0 .. S+1
#define THREADS 256

// Workspace layout (bytes)
#define CNT_OFF 0
#define H0_OFF  16384
#define H1_OFF  (16384 + 65536)
#define WS_BYTES (16384 + 2 * 65536)

// LDS: 96KB weight frags + 6KB cross-wave reduce
#define REDOFF 98304
#define LDS_BYTES (98304 + 6144)

typedef __attribute__((ext_vector_type(8))) short short8;   // 8 x bf16
typedef __attribute__((ext_vector_type(4))) float f32x4;

__device__ __forceinline__ short f2bf(float f) {
  unsigned int u = __float_as_uint(f);
  u += 0x7fffu + ((u >> 16) & 1u);        // RNE
  return (short)(u >> 16);
}
__device__ __forceinline__ float sigm(float v) { return 1.0f / (1.0f + __expf(-v)); }
__device__ __forceinline__ float tanhc(float v) {
  v = fminf(fmaxf(v, -15.0f), 15.0f);
  float e = __expf(2.0f * v);
  return (e - 1.0f) / (e + 1.0f);
}

// Cache-bypassing (coherence-point) access: sc0 sc1 = system scope, skips L1+L2.
// No waitcnt inside — caller batches loads then does VDRAIN() once (rule #18:
// asm waitcnt must be followed by sched_barrier(0) or MFMA can be hoisted past it).
#define LDG16(dst_, p_) \
  asm volatile("global_load_dwordx4 %0, %1, off sc0 sc1" : "=&v"(dst_) : "v"(p_))
#define STG2(p_, v_) \
  asm volatile("global_store_short %0, %1, off sc0 sc1" :: "v"(p_), "v"(v_))
#define VDRAIN() do { \
  asm volatile("s_waitcnt vmcnt(0)" ::: "memory"); \
  __builtin_amdgcn_sched_barrier(0); \
} while (0)

__global__ __launch_bounds__(THREADS, 1)
void gru_persist(const float* __restrict__ x,
                 const float* __restrict__ wx0, const float* __restrict__ bx0,
                 const float* __restrict__ wh0,
                 const float* __restrict__ wx1, const float* __restrict__ bx1,
                 const float* __restrict__ wh1,
                 const float* __restrict__ wy,  const float* __restrict__ by,
                 float* __restrict__ out, unsigned char* __restrict__ ws)
{
  extern __shared__ char smem[];
  short8* ldsw = (short8*)smem;                 // weight frags: frag f at byte f*1024 + lane*16
  float*  red  = (float*)(smem + REDOFF);       // cross-wave partial-acc reduce

  unsigned int*   cnt    = (unsigned int*)(ws + CNT_OFF);     // per-phase arrival counters
  unsigned short* pubH0  = (unsigned short*)(ws + H0_OFF);    // [2][B][H] bf16
  unsigned short* pubH1  = (unsigned short*)(ws + H1_OFF);    // [2][B][H] bf16

  const int tid = threadIdx.x;
  const int l   = tid & 63;
  const int wv  = tid >> 6;
  const int lr  = l & 15;      // lane row/col within 16-tile
  const int lg  = l >> 4;      // lane k-group
  const int bid = blockIdx.x;
  const int role = (bid < NA) ? 0 : (bid < NA + NB) ? 1 : 2;

  // ---------- one-time weight preload into LDS, MFMA B-fragment order ----------
  if (role == 0) {
    const int ua = bid * 16;
    for (int f = wv; f < 60; f += 4) {          // 3 gate-tiles x 20 k-tiles (K=128 x + 512 h)
      const int nt = f / 20, kt = f % 20;
      const int row = nt * 512 + ua + lr;
      const float* src = (kt < 4) ? (wx0 + (size_t)row * II + kt * 32 + lg * 8)
                                  : (wh0 + (size_t)row * HH + (kt - 4) * 32 + lg * 8);
      short8 v;
#pragma unroll
      for (int j = 0; j < 8; ++j) v[j] = f2bf(src[j]);
      ldsw[(f << 6) + l] = v;
    }
  } else if (role == 1) {
    const int ub = (bid - NA) * 16;
    for (int f = wv; f < 96; f += 4) {          // 3 gate-tiles x 32 k-tiles (K=512 x + 512 h)
      const int nt = f >> 5, kt = f & 31;
      const int row = nt * 512 + ub + lr;
      const float* src = (kt < 16) ? (wx1 + (size_t)row * HH + kt * 32 + lg * 8)
                                   : (wh1 + (size_t)row * HH + (kt - 16) * 32 + lg * 8);
      short8 v;
#pragma unroll
      for (int j = 0; j < 8; ++j) v[j] = f2bf(src[j]);
      ldsw[(f << 6) + l] = v;
    }
  } else {
    const int oy = (bid - NA - NB) * 32;
    for (int f = wv; f < 32; f += 4) {          // 2 out-tiles x 16 k-tiles
      const int nt = f >> 4, kt = f & 15;
      const int row = oy + nt * 16 + lr;
      const float* src = wy + (size_t)row * HH + kt * 32 + lg * 8;
      short8 v;
#pragma unroll
      for (int j = 0; j < 8; ++j) v[j] = f2bf(src[j]);
      ldsw[(f << 6) + l] = v;
    }
  }
  __syncthreads();

  // wave roles: mh = batch half (0:b0-15, 1:b16-31), kh = K half (split-K)
  const int mh = wv & 1;
  const int kh = wv >> 1;
  const int bA = mh * 16 + lr;         // batch index for A-fragment loads
  const int bC = mh * 16 + lg * 4;     // batch base for C-fragment rows

  int u0 = 0;
  float bz = 0.f, brr = 0.f, bg = 0.f;
  if (role == 0) u0 = bid * 16;
  else if (role == 1) u0 = (bid - NA) * 16;
  if (role <= 1 && kh == 0) {
    const float* bx = role ? bx1 : bx0;
    bz  = bx[u0 + lr];
    brr = bx[512 + u0 + lr];
    bg  = bx[1024 + u0 + lr];
  }
  int oy = 0;
  const int ynt = wv >> 1;
  float byv = 0.f;
  if (role == 2) { oy = (bid - NA - NB) * 32; byv = by[oy + ynt * 16 + lr]; }

  f32x4 hm = {0.f, 0.f, 0.f, 0.f};    // fp32 master h slice (kh0 waves of roles 0/1)

  for (int p = 0; p < PHASES; ++p) {
    // ---- prefetch x for this phase (input, immutable -> safe before barrier) ----
    float4 xr[4][2];
    const bool actx = (role == 0 && kh == 0 && p < SS);
    if (actx) {
      const float* xp = x + (size_t)bA * (SS * II) + (size_t)p * II;
#pragma unroll
      for (int t = 0; t < 4; ++t) {
        xr[t][0] = *(const float4*)(xp + t * 32 + lg * 8);
        xr[t][1] = *(const float4*)(xp + t * 32 + lg * 8 + 4);
      }
    }

    // ---- wait for all blocks to finish phase p-1 (no cache fences needed:
    //      all cross-block data moves via sc0sc1 bypass accesses) ----
    if (p > 0) {
      if (tid == 0) {
        while (__hip_atomic_load(&cnt[p - 1], __ATOMIC_RELAXED, __HIP_MEMORY_SCOPE_AGENT) < NBLK)
          __builtin_amdgcn_s_sleep(1);
      }
      __syncthreads();
    }

    const bool act01 = (role == 0) ? (p < SS) : (p >= 1 && p <= SS);
    if (role <= 1 && act01) {
      // layer0 @ phase p computes h0(p): x-input x_p, h-input h0(p-1)
      // layer1 @ phase p computes h1(p-1): x-input h0(p-1), h-input h1(p-2)
      const unsigned short* pubA  = pubH0 + ((size_t)((p - 1) & 1)) * (BB * HH);
      const unsigned short* pubB2 = pubH1 + ((size_t)(p & 1)) * (BB * HH);

      f32x4 aZ = {0,0,0,0}, aR = {0,0,0,0}, aG1 = {0,0,0,0}, aG2 = {0,0,0,0};
      short8 pf[16];

      if (role == 0) {
        const unsigned short* pa = pubA + (size_t)bA * HH;
        if (kh == 0) {
          // kts 0..9: 4 x-tiles (cached, prefetched) + 6 pub tiles (bypass)
#pragma unroll
          for (int i = 0; i < 6; ++i) LDG16(pf[i], pa + i * 32 + lg * 8);
          VDRAIN();
#pragma unroll
          for (int kt = 0; kt < 4; ++kt) {
            short8 af;
#pragma unroll
            for (int j = 0; j < 4; ++j) { af[j] = f2bf(xr[kt][0][j]); af[4 + j] = f2bf(xr[kt][1][j]); }
            short8 wz = ldsw[((0 * 20 + kt) << 6) + l];
            short8 wr = ldsw[((1 * 20 + kt) << 6) + l];
            short8 wg = ldsw[((2 * 20 + kt) << 6) + l];
            aZ  = __builtin_amdgcn_mfma_f32_16x16x32_bf16(af, wz, aZ, 0, 0, 0);
            aR  = __builtin_amdgcn_mfma_f32_16x16x32_bf16(af, wr, aR, 0, 0, 0);
            aG1 = __builtin_amdgcn_mfma_f32_16x16x32_bf16(af, wg, aG1, 0, 0, 0);
          }
#pragma unroll
          for (int kt = 4; kt < 10; ++kt) {
            short8 af = pf[kt - 4];
            short8 wz = ldsw[((0 * 20 + kt) << 6) + l];
            short8 wr = ldsw[((1 * 20 + kt) << 6) + l];
            short8 wg = ldsw[((2 * 20 + kt) << 6) + l];
            aZ  = __builtin_amdgcn_mfma_f32_16x16x32_bf16(af, wz, aZ, 0, 0, 0);
            aR  = __builtin_amdgcn_mfma_f32_16x16x32_bf16(af, wr, aR, 0, 0, 0);
            aG2 = __builtin_amdgcn_mfma_f32_16x16x32_bf16(af, wg, aG2, 0, 0, 0);
          }
        } else {
#pragma unroll
          for (int i = 0; i < 10; ++i) LDG16(pf[i], pa + (6 + i) * 32 + lg * 8);
          VDRAIN();
#pragma unroll
          for (int kt = 10; kt < 20; ++kt) {
            short8 af = pf[kt - 10];
            short8 wz = ldsw[((0 * 20 + kt) << 6) + l];
            short8 wr = ldsw[((1 * 20 + kt) << 6) + l];
            short8 wg = ldsw[((2 * 20 + kt) << 6) + l];
            aZ  = __builtin_amdgcn_mfma_f32_16x16x32_bf16(af, wz, aZ, 0, 0, 0);
            aR  = __builtin_amdgcn_mfma_f32_16x16x32_bf16(af, wr, aR, 0, 0, 0);
            aG2 = __builtin_amdgcn_mfma_f32_16x16x32_bf16(af, wg, aG2, 0, 0, 0);
          }
        }
      } else {
        if (kh == 0) {
          const unsigned short* pa = pubA + (size_t)bA * HH;
#pragma unroll
          for (int i = 0; i < 16; ++i) LDG16(pf[i], pa + i * 32 + lg * 8);
          VDRAIN();
#pragma unroll
          for (int kt = 0; kt < 16; ++kt) {
            short8 af = pf[kt];
            short8 wz = ldsw[((0 * 32 + kt) << 6) + l];
            short8 wr = ldsw[((1 * 32 + kt) << 6) + l];
            short8 wg = ldsw[((2 * 32 + kt) << 6) + l];
            aZ  = __builtin_amdgcn_mfma_f32_16x16x32_bf16(af, wz, aZ, 0, 0, 0);
            aR  = __builtin_amdgcn_mfma_f32_16x16x32_bf16(af, wr, aR, 0, 0, 0);
            aG1 = __builtin_amdgcn_mfma_f32_16x16x32_bf16(af, wg, aG1, 0, 0, 0);
          }
        } else {
          const unsigned short* pb = pubB2 + (size_t)bA * HH;
#pragma unroll
          for (int i = 0; i < 16; ++i) LDG16(pf[i], pb + i * 32 + lg * 8);
          VDRAIN();
#pragma unroll
          for (int kt = 16; kt < 32; ++kt) {
            short8 af = pf[kt - 16];
            short8 wz = ldsw[((0 * 32 + kt) << 6) + l];
            short8 wr = ldsw[((1 * 32 + kt) << 6) + l];
            short8 wg = ldsw[((2 * 32 + kt) << 6) + l];
            aZ  = __builtin_amdgcn_mfma_f32_16x16x32_bf16(af, wz, aZ, 0, 0, 0);
            aR  = __builtin_amdgcn_mfma_f32_16x16x32_bf16(af, wr, aR, 0, 0, 0);
            aG2 = __builtin_amdgcn_mfma_f32_16x16x32_bf16(af, wg, aG2, 0, 0, 0);
          }
        }
      }

      if (kh == 1) {   // publish split-K partials to LDS
#pragma unroll
        for (int r = 0; r < 4; ++r) {
          red[((mh * 3 + 0) * 4 + r) * 64 + l] = aZ[r];
          red[((mh * 3 + 1) * 4 + r) * 64 + l] = aR[r];
          red[((mh * 3 + 2) * 4 + r) * 64 + l] = aG2[r];
        }
      }
      __syncthreads();
      if (kh == 0) {   // combine + gates + publish
        unsigned short* pubO = role ? (pubH1 + ((size_t)((p - 1) & 1)) * (BB * HH))
                                    : (pubH0 + ((size_t)(p & 1)) * (BB * HH));
        const bool fin = role ? (p == SS) : (p == SS - 1);
#pragma unroll
        for (int r = 0; r < 4; ++r) {
          const float z2 = red[((mh * 3 + 0) * 4 + r) * 64 + l];
          const float r2 = red[((mh * 3 + 1) * 4 + r) * 64 + l];
          const float g2 = red[((mh * 3 + 2) * 4 + r) * 64 + l];
          const float zz = sigm(aZ[r] + z2 + bz);
          const float rr = sigm(aR[r] + r2 + brr);
          const float gg = tanhc(aG1[r] + bg + rr * (aG2[r] + g2));  // g = tanh(xg + bg + r*hg)
          const float hn = gg + zz * (hm[r] - gg);
          hm[r] = hn;
          unsigned short* pp = pubO + (size_t)(bC + r) * HH + u0 + lr;
          int hv = (int)(unsigned short)f2bf(hn);
          STG2(pp, hv);
          if (fin)
            out[(size_t)(BB * SS * OO) + (size_t)(bC + r) * (2 * HH) + (role ? HH : 0) + u0 + lr] = hn;
        }
      }
    } else if (role == 2 && p >= 2) {
      // y(p-2) = h1(p-2) @ wy^T + by
      const unsigned short* pubV = pubH1 + ((size_t)(p & 1)) * (BB * HH) + (size_t)bA * HH;
      f32x4 acc = {0,0,0,0};
      short8 pf[16];
#pragma unroll
      for (int i = 0; i < 16; ++i) LDG16(pf[i], pubV + i * 32 + lg * 8);
      VDRAIN();
#pragma unroll
      for (int kt = 0; kt < 16; ++kt) {
        short8 bw = ldsw[((ynt * 16 + kt) << 6) + l];
        acc = __builtin_amdgcn_mfma_f32_16x16x32_bf16(pf[kt], bw, acc, 0, 0, 0);
      }
#pragma unroll
      for (int r = 0; r < 4; ++r) {
        out[(size_t)(bC + r) * (SS * OO) + (size_t)(p - 2) * OO + oy + ynt * 16 + lr] = acc[r] + byv;
      }
    }

    // ---- arrive at phase p: drain own bypass stores, then one relaxed add ----
    VDRAIN();
    __syncthreads();
    if (tid == 0)
      __hip_atomic_fetch_add(&cnt[p], 1u, __ATOMIC_RELAXED, __HIP_MEMORY_SCOPE_AGENT);
  }
}

extern "C" void kernel_launch(void* const* d_in, const int* in_sizes, int n_in,
                              void* d_out, int out_size, void* d_ws, size_t ws_size,
                              hipStream_t stream) {
  (void)in_sizes; (void)n_in; (void)out_size;
  const float* x   = (const float*)d_in[0];
  const float* wx0 = (const float*)d_in[1];
  const float* bx0 = (const float*)d_in[2];
  const float* wh0 = (const float*)d_in[3];
  const float* wx1 = (const float*)d_in[4];
  const float* bx1 = (const float*)d_in[5];
  const float* wh1 = (const float*)d_in[6];
  const float* wy  = (const float*)d_in[7];
  const float* by  = (const float*)d_in[8];
  float* out = (float*)d_out;

  // zero phase counters + h publish buffers (makes every launch/replay identical)
  hipMemsetAsync(d_ws, 0, WS_BYTES, stream);
  gru_persist<<<dim3(NBLK), dim3(THREADS), LDS_BYTES, stream>>>(
      x, wx0, bx0, wh0, wx1, bx1, wh1, wy, by, out, (unsigned char*)d_ws);
  (void)ws_size;
}